// Round 3
// baseline (34070.941 us; speedup 1.0000x reference)
//
#include <hip/hip_runtime.h>

// ---------------------------------------------------------------------------
// 2-layer ReLU RNN, B=64 T=2048 IN=256 H=512 C=128.
//
// Round-3 robustness: (1) runtime input-dtype detection (fp32 vs bf16) — the
// reference is jnp.float32; reading fp32 memory as bf16 yields Inf/NaN, which
// matches rounds 1-2. A 1-wave kernel classifies x's even u16 exponent fields
// and writes a flag; all raw-input readers branch on it (wave-uniform), and
// the final store writes bf16 or fp32 to match. (2) ws-adaptive chunking over
// T (Tc in {2048,512,256,128} chosen from ws_size) so the footprint fits any
// plausible workspace; h state is carried across chunk dispatches.
//
// Per chunk c: gemm0: bufA = x[:,t0:t0+Tc,:] @ W_ih0^T + bias0   (fp16 out)
//              scan0: h written in place over bufA; h state in hx0
//              gemm1: bufB = bufA @ W_ih1^T + bias1
//              scan1: reads bufB; h state in hx1; last step -> hlast (fp32)
// Then: out = hlast @ fc_w^T + fc_b.
//
// Scan: 128 WGs x 1 wave: 4 row-groups(16 batch rows) x 32 col-groups(16 h
// cols); W_hh slice (16x512 fp16) in 64 VGPRs; per-step sync via monotonic
// per-producer flags (agent-scope atomics) + agent fences; double-buffered
// h exchange keyed by global-step parity. Spins bounded (no hang).
// ---------------------------------------------------------------------------

typedef unsigned short u16;
typedef unsigned int u32;
typedef _Float16 f16;
typedef _Float16 half8 __attribute__((ext_vector_type(8)));
typedef float float4v __attribute__((ext_vector_type(4)));

#define T_LEN 2048
#define H_DIM 512
#define B_SZ 64

__device__ __forceinline__ float bf2f(u16 u) {
    union { u32 i; float f; } v; v.i = ((u32)u) << 16; return v.f;
}
__device__ __forceinline__ u16 f2bf(float f) {
    u32 x = __float_as_uint(f);
    u32 r = (x + 0x7fffu + ((x >> 16) & 1u)) >> 16;
    return (u16)r;
}
// Flag-aware scalar load from a raw input tensor.
__device__ __forceinline__ float loadf(const void* p, size_t i, int dt) {
    return dt ? ((const float*)p)[i] : bf2f(((const u16*)p)[i]);
}
__device__ __forceinline__ half8 cvt8_bf16(uint4 v) {
    half8 h;
    h[0] = (f16)bf2f((u16)(v.x & 0xffff)); h[1] = (f16)bf2f((u16)(v.x >> 16));
    h[2] = (f16)bf2f((u16)(v.y & 0xffff)); h[3] = (f16)bf2f((u16)(v.y >> 16));
    h[4] = (f16)bf2f((u16)(v.z & 0xffff)); h[5] = (f16)bf2f((u16)(v.z >> 16));
    h[6] = (f16)bf2f((u16)(v.w & 0xffff)); h[7] = (f16)bf2f((u16)(v.w >> 16));
    return h;
}

// --------------------------- dtype detection -------------------------------
// Inspect even-index u16s of x. bf16 data (N(0,1) samples): exponent field in
// [0x60,0x8f] essentially always. fp32 data: even u16 = low mantissa half ->
// exponent-field bits uniform -> ~19% in range. Threshold at 96/128.
__global__ void detect_kernel(const u16* __restrict__ xr, int* __restrict__ dtf) {
    int lane = threadIdx.x;
    int c0 = 0, c1 = 0;
    {
        u16 u = xr[(lane * 2 + 0) * 2];
        int e = (u >> 7) & 0xff;
        c0 = (e >= 0x60 && e <= 0x8f) ? 1 : 0;
    }
    {
        u16 u = xr[(lane * 2 + 1) * 2];
        int e = (u >> 7) & 0xff;
        c1 = (e >= 0x60 && e <= 0x8f) ? 1 : 0;
    }
    int tot = __popcll(__ballot(c0)) + __popcll(__ballot(c1));
    if (lane == 0) *dtf = (tot >= 96) ? 0 : 1;   // 0 = bf16, 1 = fp32
}

// --------------------------- prep kernels ----------------------------------
__global__ void cvt_w_kernel(const void* __restrict__ in, f16* __restrict__ out,
                             int n, const int* __restrict__ dtf) {
    int dt = *dtf;
    for (int i = blockIdx.x * blockDim.x + threadIdx.x; i < n; i += gridDim.x * blockDim.x)
        out[i] = (f16)loadf(in, i, dt);
}

__global__ void bias_kernel(const void* __restrict__ bi, const void* __restrict__ bh,
                            float* __restrict__ bias, const int* __restrict__ dtf) {
    int dt = *dtf;
    int i = blockIdx.x * blockDim.x + threadIdx.x;
    if (i < H_DIM) bias[i] = loadf(bi, i, dt) + loadf(bh, i, dt);
}

__global__ void fcb_kernel(const void* __restrict__ in, float* __restrict__ out,
                           const int* __restrict__ dtf) {
    int dt = *dtf;
    int i = threadIdx.x;
    if (i < 128) out[i] = loadf(in, i, dt);
}

// --------------------------- tiled MFMA GEMM -------------------------------
// C[m,n] = sum_k A[m,k]*Bw[n,k] + bias[n], fp16 MFMA, fp16 out, N=512.
// RAW=1: A is the raw x tensor ([B,T,K] in dtf dtype), rows mapped
//        b*T + t_off + tt (chunk-local m = b*Tc + tt). RAW=0: A fp16, [rows,K].
// 64x64 tile, BK=32, 256 threads (4 waves; wave = 16 n-cols x 64 m-rows).
template<int RAW>
__global__ __launch_bounds__(256)
void gemm_tiled(const void* __restrict__ Araw, const f16* __restrict__ Bw,
                const float* __restrict__ bias, f16* __restrict__ C,
                int lgTc, int t_off, int K, const int* __restrict__ dtf)
{
    __shared__ f16 As[64][40];   // +8 pad
    __shared__ f16 Bs[64][40];
    const int dt = RAW ? *dtf : 0;
    const int m0 = blockIdx.x * 64, n0 = blockIdx.y * 64;
    const int tid = threadIdx.x;
    const int wv = tid >> 6, lane = tid & 63;
    const int lr = lane & 15, quad = lane >> 4;
    const int srow = tid >> 2, skq = tid & 3;

    float4v acc[4] = {{0.f,0.f,0.f,0.f},{0.f,0.f,0.f,0.f},{0.f,0.f,0.f,0.f},{0.f,0.f,0.f,0.f}};

    size_t arow;
    {
        int ml = m0 + srow;
        if (RAW) {
            int b = ml >> lgTc, tt = ml & ((1 << lgTc) - 1);
            arow = (size_t)b * T_LEN + t_off + tt;
        } else arow = (size_t)ml;
    }
    const f16* pb = Bw + (size_t)(n0 + srow) * K + skq * 8;

    for (int k0 = 0; k0 < K; k0 += 32) {
        half8 av;
        if (RAW) {
            if (dt) {
                const float* ap = (const float*)Araw + arow * K + k0 + skq * 8;
                float4v f0 = *(const float4v*)ap;
                float4v f1 = *(const float4v*)(ap + 4);
                av[0]=(f16)f0[0]; av[1]=(f16)f0[1]; av[2]=(f16)f0[2]; av[3]=(f16)f0[3];
                av[4]=(f16)f1[0]; av[5]=(f16)f1[1]; av[6]=(f16)f1[2]; av[7]=(f16)f1[3];
            } else {
                av = cvt8_bf16(*(const uint4*)((const u16*)Araw + arow * K + k0 + skq * 8));
            }
        } else {
            av = *(const half8*)((const f16*)Araw + arow * K + k0 + skq * 8);
        }
        half8 bv = *(const half8*)(pb + k0);
        __syncthreads();                       // prior iter's LDS reads done
        *(half8*)&As[srow][skq * 8] = av;
        *(half8*)&Bs[srow][skq * 8] = bv;
        __syncthreads();
        half8 bf = *(const half8*)&Bs[wv * 16 + lr][quad * 8];
#pragma unroll
        for (int mt = 0; mt < 4; ++mt) {
            half8 af = *(const half8*)&As[mt * 16 + lr][quad * 8];
            acc[mt] = __builtin_amdgcn_mfma_f32_16x16x32_f16(af, bf, acc[mt], 0, 0, 0);
        }
    }
    const int n = n0 + wv * 16 + lr;
    const float bval = bias[n];
#pragma unroll
    for (int mt = 0; mt < 4; ++mt) {
#pragma unroll
        for (int i = 0; i < 4; ++i) {
            int m = m0 + mt * 16 + quad * 4 + i;   // C/D: row=quad*4+reg, col=lr
            C[(size_t)m * H_DIM + n] = (f16)(acc[mt][i] + bval);
        }
    }
}

// --------------------------- recurrent scan --------------------------------
// grid=128 (1 wave): bid>>5 = row-group r (16 batch rows), bid&31 = col-group
// g (16 h cols). Whh fp16 (preconverted); slice in 64 VGPRs. preh chunk-local
// [B,Tc,H]; global step t = t0+tt; flags monotone in global step.
__global__ __launch_bounds__(64, 1)
void rnn_scan_kernel(f16* preh,                      // aliased read/write
                     const f16* __restrict__ Whh,    // [H,H] fp16
                     f16* __restrict__ hx,           // [2,B,H] fp16 exchange
                     int* __restrict__ flags,        // [4*32] monotonic counters
                     int t0, int Tc, int write_h,
                     float* __restrict__ h_last)     // [B,H] fp32 or null
{
    const int bid = blockIdx.x;
    const int r = bid >> 5, g = bid & 31;
    const int rows0 = r * 16, col0 = g * 16;
    const int lane = threadIdx.x;
    const int lr = lane & 15, quad = lane >> 4;

    half8 Bfrag[16];   // B[n=col0+lr][k=kc*32+quad*8+j]
#pragma unroll
    for (int kc = 0; kc < 16; ++kc)
        Bfrag[kc] = *(const half8*)(Whh + (size_t)(col0 + lr) * H_DIM + kc * 32 + quad * 8);

    int* myflags = flags + r * 32;
    const int row_a = rows0 + lr;

    for (int tt = 0; tt < Tc; ++tt) {
        const int t = t0 + tt;
        // Prefetch pre_t (independent of h) to overlap HBM latency with spin.
        float p[4];
#pragma unroll
        for (int i = 0; i < 4; ++i)
            p[i] = (float)preh[((size_t)(rows0 + quad * 4 + i) * Tc + tt) * H_DIM
                               + col0 + lr];

        float4v acc = {0.f, 0.f, 0.f, 0.f};
        if (t > 0) {
            int spin = 0;
            for (;;) {
                int v = __hip_atomic_load(&myflags[lane & 31], __ATOMIC_RELAXED,
                                          __HIP_MEMORY_SCOPE_AGENT);
                if (lane >= 32) v = t;
                if (__all(v >= t)) break;
                if (++spin > (1 << 20)) break;   // bounded: wrong answer, not hang
            }
            __builtin_amdgcn_fence(__ATOMIC_ACQUIRE, "agent");

            const f16* hxr = hx + (size_t)((t - 1) & 1) * B_SZ * H_DIM
                                + (size_t)row_a * H_DIM;
            float4v acc2 = {0.f, 0.f, 0.f, 0.f};
#pragma unroll
            for (int kc = 0; kc < 16; kc += 2) {   // two chains hide MFMA latency
                half8 va = *(const half8*)(hxr + kc * 32 + quad * 8);
                half8 vb = *(const half8*)(hxr + (kc + 1) * 32 + quad * 8);
                acc  = __builtin_amdgcn_mfma_f32_16x16x32_f16(va, Bfrag[kc], acc, 0, 0, 0);
                acc2 = __builtin_amdgcn_mfma_f32_16x16x32_f16(vb, Bfrag[kc + 1], acc2, 0, 0, 0);
            }
            acc += acc2;
        }

        f16* hxw = hx + (size_t)(t & 1) * B_SZ * H_DIM;
        float hv[4];
        f16 hv16[4];
#pragma unroll
        for (int i = 0; i < 4; ++i) {
            float hval = fmaxf(acc[i] + p[i], 0.f);
            hv[i] = hval;
            hv16[i] = (f16)hval;
            hxw[(size_t)(rows0 + quad * 4 + i) * H_DIM + col0 + lr] = hv16[i];
        }
        __builtin_amdgcn_fence(__ATOMIC_RELEASE, "agent");
        if (lane == 0)
            __hip_atomic_store(&myflags[g], t + 1, __ATOMIC_RELAXED,
                               __HIP_MEMORY_SCOPE_AGENT);
        // Non-protocol outputs after the flag (kernel end flushes them).
        if (write_h) {
#pragma unroll
            for (int i = 0; i < 4; ++i)
                preh[((size_t)(rows0 + quad * 4 + i) * Tc + tt) * H_DIM
                     + col0 + lr] = hv16[i];
        }
        if (h_last && t == T_LEN - 1) {
#pragma unroll
            for (int i = 0; i < 4; ++i)
                h_last[(size_t)(rows0 + quad * 4 + i) * H_DIM + col0 + lr] = hv[i];
        }
    }
}

// --------------------------- final FC --------------------------------------
__global__ void fc_kernel(const float* __restrict__ hlast, const f16* __restrict__ fcw,
                          const float* __restrict__ fcb, void* __restrict__ out,
                          const int* __restrict__ dtf) {
    int b = blockIdx.x, c = threadIdx.x;
    const float* hrow = hlast + b * H_DIM;
    const f16* wrow = fcw + (size_t)c * H_DIM;
    float s = fcb[c];
    for (int h0 = 0; h0 < H_DIM; h0 += 8) {
        half8 w = *(const half8*)(wrow + h0);
#pragma unroll
        for (int j = 0; j < 8; ++j) s += hrow[h0 + j] * (float)w[j];
    }
    if (*dtf) ((float*)out)[b * 128 + c] = s;
    else      ((u16*)out)[b * 128 + c] = f2bf(s);
}

// --------------------------- launch ----------------------------------------
extern "C" void kernel_launch(void* const* d_in, const int* in_sizes, int n_in,
                              void* d_out, int out_size, void* d_ws, size_t ws_size,
                              hipStream_t stream)
{
    const void* x     = d_in[0];
    const void* W_ih0 = d_in[1];
    const void* W_hh0 = d_in[2];
    const void* b_ih0 = d_in[3];
    const void* b_hh0 = d_in[4];
    const void* W_ih1 = d_in[5];
    const void* W_hh1 = d_in[6];
    const void* b_ih1 = d_in[7];
    const void* b_hh1 = d_in[8];
    const void* fc_w  = d_in[9];
    const void* fc_b  = d_in[10];

    char* ws = (char*)d_ws;
    // Misc region (first 4 MB), all offsets 64B-aligned:
    int*   dtf   = (int*)(ws + 0);            //     64 B
    int*   flags = (int*)(ws + 64);           //   1024 B (2 layers x 128)
    float* bias0 = (float*)(ws + 4096);       //   2048 B
    float* bias1 = (float*)(ws + 6144);       //   2048 B
    float* fcbf  = (float*)(ws + 8192);       //    512 B
    float* hlast = (float*)(ws + 16384);      // 131072 B [64,512] fp32
    f16*   hx0   = (f16*)(ws + 147456);       // 131072 B [2,64,512] fp16
    f16*   hx1   = (f16*)(ws + 278528);       // 131072 B
    f16*   Wih0f = (f16*)(ws + 409600);       // 262144 B [512,256]
    f16*   Whh0f = (f16*)(ws + 671744);       // 524288 B [512,512]
    f16*   Wih1f = (f16*)(ws + 1196032);      // 524288 B
    f16*   Whh1f = (f16*)(ws + 1720320);      // 524288 B
    f16*   fcwf  = (f16*)(ws + 2244608);      // 131072 B [128,512]

    // Chunk length chosen from ws_size (fixed per problem -> same work/call).
    const size_t misc = 4u << 20;
    int Tc = 128;
    {
        auto need = [&](int tc) {
            return misc + 2ull * B_SZ * (size_t)tc * H_DIM * 2;
        };
        if (ws_size >= need(2048)) Tc = 2048;
        else if (ws_size >= need(512)) Tc = 512;
        else if (ws_size >= need(256)) Tc = 256;
        else Tc = 128;
    }
    int lgTc = 31 - __builtin_clz((unsigned)Tc);
    const size_t bufbytes = (size_t)B_SZ * Tc * H_DIM * 2;
    f16* bufA = (f16*)(ws + misc);
    f16* bufB = (f16*)(ws + misc + bufbytes);

    hipMemsetAsync(flags, 0, 1024, stream);
    detect_kernel<<<dim3(1), dim3(64), 0, stream>>>((const u16*)x, dtf);
    cvt_w_kernel<<<dim3(512), dim3(256), 0, stream>>>(W_ih0, Wih0f, H_DIM * 256, dtf);
    cvt_w_kernel<<<dim3(1024), dim3(256), 0, stream>>>(W_hh0, Whh0f, H_DIM * H_DIM, dtf);
    cvt_w_kernel<<<dim3(1024), dim3(256), 0, stream>>>(W_ih1, Wih1f, H_DIM * H_DIM, dtf);
    cvt_w_kernel<<<dim3(1024), dim3(256), 0, stream>>>(W_hh1, Whh1f, H_DIM * H_DIM, dtf);
    cvt_w_kernel<<<dim3(256), dim3(256), 0, stream>>>(fc_w, fcwf, 128 * H_DIM, dtf);
    bias_kernel<<<dim3(2), dim3(256), 0, stream>>>(b_ih0, b_hh0, bias0, dtf);
    bias_kernel<<<dim3(2), dim3(256), 0, stream>>>(b_ih1, b_hh1, bias1, dtf);
    fcb_kernel<<<dim3(1), dim3(128), 0, stream>>>(fc_b, fcbf, dtf);

    const int NC = T_LEN / Tc;
    const int mblocks = B_SZ * Tc / 64;
    for (int c = 0; c < NC; ++c) {
        const int t0 = c * Tc;
        gemm_tiled<1><<<dim3(mblocks, 8), 256, 0, stream>>>(
            x, Wih0f, bias0, bufA, lgTc, t0, 256, dtf);
        rnn_scan_kernel<<<dim3(128), 64, 0, stream>>>(
            bufA, Whh0f, hx0, flags, t0, Tc, 1, nullptr);
        gemm_tiled<0><<<dim3(mblocks, 8), 256, 0, stream>>>(
            bufA, Wih1f, bias1, bufB, lgTc, 0, 512, dtf);
        rnn_scan_kernel<<<dim3(128), 64, 0, stream>>>(
            bufB, Whh1f, hx1, flags + 128, t0, Tc, 0, hlast);
    }
    fc_kernel<<<dim3(B_SZ), dim3(128), 0, stream>>>(hlast, fcwf, fcbf, d_out, dtf);
}

// Round 4
// 32464.462 us; speedup vs baseline: 1.0495x; 1.0495x over previous
//
#include <hip/hip_runtime.h>

// ---------------------------------------------------------------------------
// 2-layer ReLU RNN, B=64 T=2048 IN=256 H=512 C=128. Inputs fp32 (runtime
// dtype detect kept for robustness), output matches input dtype.
//
// Round-4 change: the scan's cross-WG flag/fence protocol (8.1 us/step, L2
// wbl2/inv per step) is replaced by a fully intra-WG design. Batch row-groups
// are independent, so grid = 4 WGs x 1024 thr (16 waves); WG owns 16 batch
// rows x all 512 h-cols. h exchange lives in double-buffered LDS (2x16KB,
// XOR-swizzled granules -> only 2-way bank aliasing) with ONE __syncthreads
// per step. W_hh slice (32 cols x 512 K fp16) per wave in 128 VGPRs.
// Floor: 512 MFMA/step on 1 CU ~ 0.86 us/step (matrix-pipe bound).
//
// Pipeline per chunk (Tc adaptive to ws_size; Tc=2048 => single chunk):
//   gemm0: bufA = x[:,t0:+Tc,:] @ W_ih0^T + bias0   (fp16)
//   scan0: h0 in place over bufA; carry in hc0
//   gemm1: bufB = bufA @ W_ih1^T + bias1
//   scan1: carry in hc1; final step -> hlast (fp32)
// Then fc: out = hlast @ fc_w^T + fc_b.
// ---------------------------------------------------------------------------

typedef unsigned short u16;
typedef unsigned int u32;
typedef _Float16 f16;
typedef _Float16 half8 __attribute__((ext_vector_type(8)));
typedef float float4v __attribute__((ext_vector_type(4)));

#define T_LEN 2048
#define H_DIM 512
#define B_SZ 64

__device__ __forceinline__ float bf2f(u16 u) {
    union { u32 i; float f; } v; v.i = ((u32)u) << 16; return v.f;
}
__device__ __forceinline__ u16 f2bf(float f) {
    u32 x = __float_as_uint(f);
    u32 r = (x + 0x7fffu + ((x >> 16) & 1u)) >> 16;
    return (u16)r;
}
__device__ __forceinline__ float loadf(const void* p, size_t i, int dt) {
    return dt ? ((const float*)p)[i] : bf2f(((const u16*)p)[i]);
}
__device__ __forceinline__ half8 cvt8_bf16(uint4 v) {
    half8 h;
    h[0] = (f16)bf2f((u16)(v.x & 0xffff)); h[1] = (f16)bf2f((u16)(v.x >> 16));
    h[2] = (f16)bf2f((u16)(v.y & 0xffff)); h[3] = (f16)bf2f((u16)(v.y >> 16));
    h[4] = (f16)bf2f((u16)(v.z & 0xffff)); h[5] = (f16)bf2f((u16)(v.z >> 16));
    h[6] = (f16)bf2f((u16)(v.w & 0xffff)); h[7] = (f16)bf2f((u16)(v.w >> 16));
    return h;
}

// --------------------------- dtype detection -------------------------------
__global__ void detect_kernel(const u16* __restrict__ xr, int* __restrict__ dtf) {
    int lane = threadIdx.x;
    u16 u0 = xr[(lane * 2 + 0) * 2];
    u16 u1 = xr[(lane * 2 + 1) * 2];
    int e0 = (u0 >> 7) & 0xff, e1 = (u1 >> 7) & 0xff;
    int c0 = (e0 >= 0x60 && e0 <= 0x8f) ? 1 : 0;
    int c1 = (e1 >= 0x60 && e1 <= 0x8f) ? 1 : 0;
    int tot = __popcll(__ballot(c0)) + __popcll(__ballot(c1));
    if (lane == 0) *dtf = (tot >= 96) ? 0 : 1;   // 0 = bf16, 1 = fp32
}

// --------------------------- prep kernels ----------------------------------
__global__ void cvt_w_kernel(const void* __restrict__ in, f16* __restrict__ out,
                             int n, const int* __restrict__ dtf) {
    int dt = *dtf;
    for (int i = blockIdx.x * blockDim.x + threadIdx.x; i < n; i += gridDim.x * blockDim.x)
        out[i] = (f16)loadf(in, i, dt);
}

__global__ void bias_kernel(const void* __restrict__ bi, const void* __restrict__ bh,
                            float* __restrict__ bias, const int* __restrict__ dtf) {
    int dt = *dtf;
    int i = blockIdx.x * blockDim.x + threadIdx.x;
    if (i < H_DIM) bias[i] = loadf(bi, i, dt) + loadf(bh, i, dt);
}

__global__ void fcb_kernel(const void* __restrict__ in, float* __restrict__ out,
                           const int* __restrict__ dtf) {
    int dt = *dtf;
    int i = threadIdx.x;
    if (i < 128) out[i] = loadf(in, i, dt);
}

// --------------------------- tiled MFMA GEMM -------------------------------
// C[m,n] = sum_k A[m,k]*Bw[n,k] + bias[n], fp16 MFMA, fp16 out, N=512.
// RAW=1: A is raw x ([B,T,K], dtf dtype), chunk-local row m -> b*T + t0+tt.
template<int RAW>
__global__ __launch_bounds__(256)
void gemm_tiled(const void* __restrict__ Araw, const f16* __restrict__ Bw,
                const float* __restrict__ bias, f16* __restrict__ C,
                int lgTc, int t_off, int K, const int* __restrict__ dtf)
{
    __shared__ f16 As[64][40];
    __shared__ f16 Bs[64][40];
    const int dt = RAW ? *dtf : 0;
    const int m0 = blockIdx.x * 64, n0 = blockIdx.y * 64;
    const int tid = threadIdx.x;
    const int wv = tid >> 6, lane = tid & 63;
    const int lr = lane & 15, quad = lane >> 4;
    const int srow = tid >> 2, skq = tid & 3;

    float4v acc[4] = {{0.f,0.f,0.f,0.f},{0.f,0.f,0.f,0.f},{0.f,0.f,0.f,0.f},{0.f,0.f,0.f,0.f}};

    size_t arow;
    {
        int ml = m0 + srow;
        if (RAW) {
            int b = ml >> lgTc, tt = ml & ((1 << lgTc) - 1);
            arow = (size_t)b * T_LEN + t_off + tt;
        } else arow = (size_t)ml;
    }
    const f16* pb = Bw + (size_t)(n0 + srow) * K + skq * 8;

    for (int k0 = 0; k0 < K; k0 += 32) {
        half8 av;
        if (RAW) {
            if (dt) {
                const float* ap = (const float*)Araw + arow * K + k0 + skq * 8;
                float4v f0 = *(const float4v*)ap;
                float4v f1 = *(const float4v*)(ap + 4);
                av[0]=(f16)f0[0]; av[1]=(f16)f0[1]; av[2]=(f16)f0[2]; av[3]=(f16)f0[3];
                av[4]=(f16)f1[0]; av[5]=(f16)f1[1]; av[6]=(f16)f1[2]; av[7]=(f16)f1[3];
            } else {
                av = cvt8_bf16(*(const uint4*)((const u16*)Araw + arow * K + k0 + skq * 8));
            }
        } else {
            av = *(const half8*)((const f16*)Araw + arow * K + k0 + skq * 8);
        }
        half8 bv = *(const half8*)(pb + k0);
        __syncthreads();
        *(half8*)&As[srow][skq * 8] = av;
        *(half8*)&Bs[srow][skq * 8] = bv;
        __syncthreads();
        half8 bf = *(const half8*)&Bs[wv * 16 + lr][quad * 8];
#pragma unroll
        for (int mt = 0; mt < 4; ++mt) {
            half8 af = *(const half8*)&As[mt * 16 + lr][quad * 8];
            acc[mt] = __builtin_amdgcn_mfma_f32_16x16x32_f16(af, bf, acc[mt], 0, 0, 0);
        }
    }
    const int n = n0 + wv * 16 + lr;
    const float bval = bias[n];
#pragma unroll
    for (int mt = 0; mt < 4; ++mt) {
#pragma unroll
        for (int i = 0; i < 4; ++i) {
            int m = m0 + mt * 16 + quad * 4 + i;
            C[(size_t)m * H_DIM + n] = (f16)(acc[mt][i] + bval);
        }
    }
}

// --------------------------- recurrent scan --------------------------------
// grid = 4 WGs x 1024 thr (16 waves). WG r owns batch rows r*16..r*16+15 and
// all 512 cols. Wave w computes cols [w*32, w*32+32): two 16x16x32 MFMA
// accumulator chains over K=512. W_hh slice in 128 VGPRs. h_{t} lives in LDS
// hbuf[t&1] (XOR-swizzled granules); one __syncthreads per step.
__global__ __launch_bounds__(1024, 1)
void rnn_scan_kernel(f16* preh,                      // [B,Tc,H] chunk-local, aliased r/w
                     const f16* __restrict__ Whh,    // [H,H] fp16
                     f16* __restrict__ hcarry,       // [B,H] fp16 chunk carry
                     int t0, int Tc, int write_h,
                     float* __restrict__ h_last)     // [B,H] fp32 or null
{
    __shared__ f16 hbuf[2][16 * 512];   // 2 x 16 KB, swizzled
    const int rows0 = blockIdx.x * 16;
    const int tid = threadIdx.x;
    const int w = tid >> 6, lane = tid & 63;
    const int lr = lane & 15, quad = lane >> 4;
    const int c0 = w * 32;

    // W_hh B-frags: Bf[j][kc] = W[n=c0+j*16+lr][k=kc*32+quad*8 ..+8]
    half8 Bf[2][16];
#pragma unroll
    for (int j = 0; j < 2; ++j)
#pragma unroll
        for (int kc = 0; kc < 16; ++kc)
            Bf[j][kc] = *(const half8*)(Whh + (size_t)(c0 + j * 16 + lr) * H_DIM
                                        + kc * 32 + quad * 8);

    // Prefill h_{t0-1} into hbuf[(t0-1)&1] from carry (chunked runs only).
    if (t0 > 0) {
        int row = tid >> 6;            // reuse: 1024 thr = 16 rows x 64 granules
        int g = tid & 63;
        *(half8*)&hbuf[(t0 - 1) & 1][row * 512 + ((g ^ (row & 7)) * 8)] =
            *(const half8*)(hcarry + (size_t)(rows0 + row) * H_DIM + g * 8);
    }
    __syncthreads();

    const int rd = quad;   // A-frag k-offset granule piece
    for (int tt = 0; tt < Tc; ++tt) {
        const int t = t0 + tt;
        // Prefetch pre_t (independent of h chain).
        float p[2][4];
#pragma unroll
        for (int j = 0; j < 2; ++j)
#pragma unroll
            for (int i = 0; i < 4; ++i)
                p[j][i] = (float)preh[((size_t)(rows0 + quad * 4 + i) * Tc + tt) * H_DIM
                                      + c0 + j * 16 + lr];

        float4v acc0 = {0.f,0.f,0.f,0.f}, acc1 = {0.f,0.f,0.f,0.f};
        if (t > 0) {
            const f16* hb = hbuf[(t - 1) & 1];
#pragma unroll
            for (int kc = 0; kc < 16; ++kc) {
                half8 a = *(const half8*)&hb[lr * 512 + (((kc * 4 + rd) ^ (lr & 7)) * 8)];
                acc0 = __builtin_amdgcn_mfma_f32_16x16x32_f16(a, Bf[0][kc], acc0, 0, 0, 0);
                acc1 = __builtin_amdgcn_mfma_f32_16x16x32_f16(a, Bf[1][kc], acc1, 0, 0, 0);
            }
        }

        f16* hw = hbuf[t & 1];
        f16 hv[2][4];
#pragma unroll
        for (int j = 0; j < 2; ++j) {
            const float4v& a = j ? acc1 : acc0;
#pragma unroll
            for (int i = 0; i < 4; ++i) {
                float hval = fmaxf(a[i] + p[j][i], 0.f);
                hv[j][i] = (f16)hval;
                int row = quad * 4 + i, col = c0 + j * 16 + lr;
                hw[row * 512 + ((col >> 3) ^ (row & 7)) * 8 + (col & 7)] = hv[j][i];
            }
        }
        // Non-LDS outputs (no ordering vs barrier needed beyond kernel end).
        if (write_h) {
#pragma unroll
            for (int j = 0; j < 2; ++j)
#pragma unroll
                for (int i = 0; i < 4; ++i)
                    preh[((size_t)(rows0 + quad * 4 + i) * Tc + tt) * H_DIM
                         + c0 + j * 16 + lr] = hv[j][i];
        }
        if (h_last && t == T_LEN - 1) {
#pragma unroll
            for (int j = 0; j < 2; ++j)
#pragma unroll
                for (int i = 0; i < 4; ++i)
                    h_last[(size_t)(rows0 + quad * 4 + i) * H_DIM + c0 + j * 16 + lr] =
                        (float)hv[j][i];
        }
        if (tt == Tc - 1) {
#pragma unroll
            for (int j = 0; j < 2; ++j)
#pragma unroll
                for (int i = 0; i < 4; ++i)
                    hcarry[(size_t)(rows0 + quad * 4 + i) * H_DIM + c0 + j * 16 + lr] =
                        hv[j][i];
        }
        __syncthreads();   // h_t writes visible before step t+1 reads
    }
}

// --------------------------- final FC --------------------------------------
__global__ void fc_kernel(const float* __restrict__ hlast, const f16* __restrict__ fcw,
                          const float* __restrict__ fcb, void* __restrict__ out,
                          const int* __restrict__ dtf) {
    int b = blockIdx.x, c = threadIdx.x;
    const float* hrow = hlast + b * H_DIM;
    const f16* wrow = fcw + (size_t)c * H_DIM;
    float s = fcb[c];
    for (int h0 = 0; h0 < H_DIM; h0 += 8) {
        half8 w = *(const half8*)(wrow + h0);
#pragma unroll
        for (int j = 0; j < 8; ++j) s += hrow[h0 + j] * (float)w[j];
    }
    if (*dtf) ((float*)out)[b * 128 + c] = s;
    else      ((u16*)out)[b * 128 + c] = f2bf(s);
}

// --------------------------- launch ----------------------------------------
extern "C" void kernel_launch(void* const* d_in, const int* in_sizes, int n_in,
                              void* d_out, int out_size, void* d_ws, size_t ws_size,
                              hipStream_t stream)
{
    const void* x     = d_in[0];
    const void* W_ih0 = d_in[1];
    const void* W_hh0 = d_in[2];
    const void* b_ih0 = d_in[3];
    const void* b_hh0 = d_in[4];
    const void* W_ih1 = d_in[5];
    const void* W_hh1 = d_in[6];
    const void* b_ih1 = d_in[7];
    const void* b_hh1 = d_in[8];
    const void* fc_w  = d_in[9];
    const void* fc_b  = d_in[10];

    char* ws = (char*)d_ws;
    int*   dtf   = (int*)(ws + 0);            //     64 B
    float* bias0 = (float*)(ws + 4096);       //   2048 B
    float* bias1 = (float*)(ws + 6144);       //   2048 B
    float* fcbf  = (float*)(ws + 8192);       //    512 B
    float* hlast = (float*)(ws + 16384);      // 131072 B [64,512] fp32
    f16*   hc0   = (f16*)(ws + 147456);       //  65536 B [64,512] fp16 carry
    f16*   hc1   = (f16*)(ws + 212992);       //  65536 B
    f16*   Wih0f = (f16*)(ws + 409600);       // 262144 B
    f16*   Whh0f = (f16*)(ws + 671744);       // 524288 B
    f16*   Wih1f = (f16*)(ws + 1196032);      // 524288 B
    f16*   Whh1f = (f16*)(ws + 1720320);      // 524288 B
    f16*   fcwf  = (f16*)(ws + 2244608);      // 131072 B

    const size_t misc = 4u << 20;
    int Tc = 128;
    {
        auto need = [&](int tc) {
            return misc + 2ull * B_SZ * (size_t)tc * H_DIM * 2;
        };
        if (ws_size >= need(2048)) Tc = 2048;
        else if (ws_size >= need(512)) Tc = 512;
        else if (ws_size >= need(256)) Tc = 256;
        else Tc = 128;
    }
    int lgTc = 31 - __builtin_clz((unsigned)Tc);
    const size_t bufbytes = (size_t)B_SZ * Tc * H_DIM * 2;
    f16* bufA = (f16*)(ws + misc);
    f16* bufB = (f16*)(ws + misc + bufbytes);

    detect_kernel<<<dim3(1), dim3(64), 0, stream>>>((const u16*)x, dtf);
    cvt_w_kernel<<<dim3(512), dim3(256), 0, stream>>>(W_ih0, Wih0f, H_DIM * 256, dtf);
    cvt_w_kernel<<<dim3(1024), dim3(256), 0, stream>>>(W_hh0, Whh0f, H_DIM * H_DIM, dtf);
    cvt_w_kernel<<<dim3(1024), dim3(256), 0, stream>>>(W_ih1, Wih1f, H_DIM * H_DIM, dtf);
    cvt_w_kernel<<<dim3(1024), dim3(256), 0, stream>>>(W_hh1, Whh1f, H_DIM * H_DIM, dtf);
    cvt_w_kernel<<<dim3(256), dim3(256), 0, stream>>>(fc_w, fcwf, 128 * H_DIM, dtf);
    bias_kernel<<<dim3(2), dim3(256), 0, stream>>>(b_ih0, b_hh0, bias0, dtf);
    bias_kernel<<<dim3(2), dim3(256), 0, stream>>>(b_ih1, b_hh1, bias1, dtf);
    fcb_kernel<<<dim3(1), dim3(128), 0, stream>>>(fc_b, fcbf, dtf);

    const int NC = T_LEN / Tc;
    const int mblocks = B_SZ * Tc / 64;
    for (int c = 0; c < NC; ++c) {
        const int t0 = c * Tc;
        gemm_tiled<1><<<dim3(mblocks, 8), 256, 0, stream>>>(
            x, Wih0f, bias0, bufA, lgTc, t0, 256, dtf);
        rnn_scan_kernel<<<dim3(4), 1024, 0, stream>>>(
            bufA, Whh0f, hc0, t0, Tc, 1, nullptr);
        gemm_tiled<0><<<dim3(mblocks, 8), 256, 0, stream>>>(
            bufA, Wih1f, bias1, bufB, lgTc, 0, 512, dtf);
        rnn_scan_kernel<<<dim3(4), 1024, 0, stream>>>(
            bufB, Whh1f, hc1, t0, Tc, 0, hlast);
    }
    fc_kernel<<<dim3(B_SZ), dim3(128), 0, stream>>>(hlast, fcwf, fcbf, d_out, dtf);
}

// Round 5
// 11896.187 us; speedup vs baseline: 2.8640x; 2.7290x over previous
//
#include <hip/hip_runtime.h>

// ---------------------------------------------------------------------------
// 2-layer ReLU RNN, B=64 T=2048 IN=256 H=512 C=128. fp32 inputs (runtime
// dtype detect kept), output dtype matches input.
//
// Round-5 scan: 16 WGs x 256 thr (4 waves, 1 wave/SIMD -> 512-VGPR budget).
// WG (r,cg): 16 batch rows x 128 cols. W-slice 32 cols x 512 per wave in
// 128 VGPRs (round-4 spilled at 16 waves/WG; this is the fix). h exchange:
// u64 words (4 f16, h>=0) with 2-bit step tag in the 4 sign bits ->
// self-validating; published via device-scope atomic exchange, consumed via
// atomic fetch_or(0) spins (RMWs execute at the coherence point; NO fences,
// no wbl2/inv). LDS double-buffered h stage (granule-XOR swizzle).
// Max producer lead on a same-buffer word is 2 steps -> tag always differs
// on stale data. 0xAA poison has sign bits = 1 -> rejected at t=0,1.
// ---------------------------------------------------------------------------

typedef unsigned short u16;
typedef unsigned int u32;
typedef unsigned long long u64;
typedef _Float16 f16;
typedef _Float16 half8 __attribute__((ext_vector_type(8)));
typedef float float4v __attribute__((ext_vector_type(4)));

#define T_LEN 2048
#define H_DIM 512
#define B_SZ 64
#define SGN 0x8000800080008000ull
#define VMASK 0x7fff7fff7fff7fffull
#define SPIN_LIM (1 << 15)

__device__ __forceinline__ float bf2f(u16 u) {
    union { u32 i; float f; } v; v.i = ((u32)u) << 16; return v.f;
}
__device__ __forceinline__ u16 f2bf(float f) {
    u32 x = __float_as_uint(f);
    u32 r = (x + 0x7fffu + ((x >> 16) & 1u)) >> 16;
    return (u16)r;
}
__device__ __forceinline__ float loadf(const void* p, size_t i, int dt) {
    return dt ? ((const float*)p)[i] : bf2f(((const u16*)p)[i]);
}
__device__ __forceinline__ half8 cvt8_bf16(uint4 v) {
    half8 h;
    h[0] = (f16)bf2f((u16)(v.x & 0xffff)); h[1] = (f16)bf2f((u16)(v.x >> 16));
    h[2] = (f16)bf2f((u16)(v.y & 0xffff)); h[3] = (f16)bf2f((u16)(v.y >> 16));
    h[4] = (f16)bf2f((u16)(v.z & 0xffff)); h[5] = (f16)bf2f((u16)(v.z >> 16));
    h[6] = (f16)bf2f((u16)(v.w & 0xffff)); h[7] = (f16)bf2f((u16)(v.w >> 16));
    return h;
}
// 2-bit tag for step t, encoded in the 4 f16 sign bits of a u64.
__device__ __forceinline__ u64 tagmask(int t) {
    int tg = (t >> 1) & 3;
    return ((tg & 1) ? 0x0000800000008000ull : 0ull) |
           ((tg & 2) ? 0x8000000080000000ull : 0ull);
}

// --------------------------- dtype detection -------------------------------
__global__ void detect_kernel(const u16* __restrict__ xr, int* __restrict__ dtf) {
    int lane = threadIdx.x;
    u16 u0 = xr[(lane * 2 + 0) * 2];
    u16 u1 = xr[(lane * 2 + 1) * 2];
    int e0 = (u0 >> 7) & 0xff, e1 = (u1 >> 7) & 0xff;
    int c0 = (e0 >= 0x60 && e0 <= 0x8f) ? 1 : 0;
    int c1 = (e1 >= 0x60 && e1 <= 0x8f) ? 1 : 0;
    int tot = __popcll(__ballot(c0)) + __popcll(__ballot(c1));
    if (lane == 0) *dtf = (tot >= 96) ? 0 : 1;   // 0 = bf16, 1 = fp32
}

// --------------------------- prep kernels ----------------------------------
__global__ void cvt_w_kernel(const void* __restrict__ in, f16* __restrict__ out,
                             int n, const int* __restrict__ dtf) {
    int dt = *dtf;
    for (int i = blockIdx.x * blockDim.x + threadIdx.x; i < n; i += gridDim.x * blockDim.x)
        out[i] = (f16)loadf(in, i, dt);
}

__global__ void bias_kernel(const void* __restrict__ bi, const void* __restrict__ bh,
                            float* __restrict__ bias, const int* __restrict__ dtf) {
    int dt = *dtf;
    int i = blockIdx.x * blockDim.x + threadIdx.x;
    if (i < H_DIM) bias[i] = loadf(bi, i, dt) + loadf(bh, i, dt);
}

__global__ void fcb_kernel(const void* __restrict__ in, float* __restrict__ out,
                           const int* __restrict__ dtf) {
    int i = threadIdx.x;
    if (i < 128) out[i] = loadf(in, i, *dtf);
}

// --------------------------- tiled MFMA GEMM -------------------------------
// C[m,n] = sum_k A[m,k]*Bw[n,k] + bias[n], fp16 MFMA, fp16 out, N=512.
// RAW=1: A is raw x ([B,T,K], dtf dtype), chunk-local row m -> b*T + t0+tt.
template<int RAW>
__global__ __launch_bounds__(256)
void gemm_tiled(const void* __restrict__ Araw, const f16* __restrict__ Bw,
                const float* __restrict__ bias, f16* __restrict__ C,
                int lgTc, int t_off, int K, const int* __restrict__ dtf)
{
    __shared__ f16 As[64][40];
    __shared__ f16 Bs[64][40];
    const int dt = RAW ? *dtf : 0;
    const int m0 = blockIdx.x * 64, n0 = blockIdx.y * 64;
    const int tid = threadIdx.x;
    const int wv = tid >> 6, lane = tid & 63;
    const int lr = lane & 15, quad = lane >> 4;
    const int srow = tid >> 2, skq = tid & 3;

    float4v acc[4] = {{0.f,0.f,0.f,0.f},{0.f,0.f,0.f,0.f},{0.f,0.f,0.f,0.f},{0.f,0.f,0.f,0.f}};

    size_t arow;
    {
        int ml = m0 + srow;
        if (RAW) {
            int b = ml >> lgTc, tt = ml & ((1 << lgTc) - 1);
            arow = (size_t)b * T_LEN + t_off + tt;
        } else arow = (size_t)ml;
    }
    const f16* pb = Bw + (size_t)(n0 + srow) * K + skq * 8;

    for (int k0 = 0; k0 < K; k0 += 32) {
        half8 av;
        if (RAW) {
            if (dt) {
                const float* ap = (const float*)Araw + arow * K + k0 + skq * 8;
                float4v f0 = *(const float4v*)ap;
                float4v f1 = *(const float4v*)(ap + 4);
                av[0]=(f16)f0[0]; av[1]=(f16)f0[1]; av[2]=(f16)f0[2]; av[3]=(f16)f0[3];
                av[4]=(f16)f1[0]; av[5]=(f16)f1[1]; av[6]=(f16)f1[2]; av[7]=(f16)f1[3];
            } else {
                av = cvt8_bf16(*(const uint4*)((const u16*)Araw + arow * K + k0 + skq * 8));
            }
        } else {
            av = *(const half8*)((const f16*)Araw + arow * K + k0 + skq * 8);
        }
        half8 bv = *(const half8*)(pb + k0);
        __syncthreads();
        *(half8*)&As[srow][skq * 8] = av;
        *(half8*)&Bs[srow][skq * 8] = bv;
        __syncthreads();
        half8 bf = *(const half8*)&Bs[wv * 16 + lr][quad * 8];
#pragma unroll
        for (int mt = 0; mt < 4; ++mt) {
            half8 af = *(const half8*)&As[mt * 16 + lr][quad * 8];
            acc[mt] = __builtin_amdgcn_mfma_f32_16x16x32_f16(af, bf, acc[mt], 0, 0, 0);
        }
    }
    const int n = n0 + wv * 16 + lr;
    const float bval = bias[n];
#pragma unroll
    for (int mt = 0; mt < 4; ++mt) {
#pragma unroll
        for (int i = 0; i < 4; ++i) {
            int m = m0 + mt * 16 + quad * 4 + i;
            C[(size_t)m * H_DIM + n] = (f16)(acc[mt][i] + bval);
        }
    }
}

// --------------------------- recurrent scan --------------------------------
// grid = 16: WG (r = bid>>2, cg = bid&3) -> batch rows [r*16,+16), cols
// [cg*128,+128). 256 thr = 4 waves; wave w: cols [cg*128+w*32,+32).
// hex: [2][64][128] u64 exchange (double-buffered by t&1, 2-bit sign tag).
__global__ __launch_bounds__(256, 1)
void rnn_scan_kernel(f16* preh,                      // [B,Tc,H] chunk-local
                     const f16* __restrict__ Whh,    // [H,H] fp16
                     u64* __restrict__ hex,          // [2][64][128]
                     f16* __restrict__ hcarry,       // [B,H] chunk carry
                     int t0, int Tc, int write_h,
                     float* __restrict__ h_last)     // [B,H] fp32 or null
{
    __shared__ f16 stage[2][16 * 512];   // 2 x 16KB, granule-XOR swizzled
    const int bid = blockIdx.x;
    const int r = bid >> 2, cg = bid & 3;
    const int rows0 = r * 16;
    const int tid = threadIdx.x;
    const int w = tid >> 6, lane = tid & 63;
    const int lr = lane & 15, quad = lane >> 4;
    const int c0w = cg * 128 + w * 32;

    // W-slice in registers: Bf[j][kc] = W[n=c0w+j*16+lr][k=kc*32+quad*8..+8]
    half8 Bf[2][16];
#pragma unroll
    for (int j = 0; j < 2; ++j)
#pragma unroll
        for (int kc = 0; kc < 16; ++kc)
            Bf[j][kc] = *(const half8*)(Whh + (size_t)(c0w + j * 16 + lr) * H_DIM
                                        + kc * 32 + quad * 8);

    // Remote-read assignment: thread covers u64-cols [rc8, rc8+8) of row rrow.
    const int rrow = tid >> 4;
    const int rc8 = (tid & 15) * 8;
    const bool mine = ((tid & 15) >> 2) == cg;   // all 8 in own slice -> skip

    // Prefill h_{t0-1} from carry (chunked continuation).
    if (t0 > 0) {
        int row = tid >> 4, g0 = (tid & 15) * 4;
#pragma unroll
        for (int gq = 0; gq < 4; ++gq) {
            int g = g0 + gq;
            *(uint4*)&stage[(t0 - 1) & 1][row * 512 + ((g ^ (row & 7)) * 8)] =
                *(const uint4*)(hcarry + (size_t)(rows0 + row) * H_DIM + g * 8);
        }
    }
    __syncthreads();

    for (int tt = 0; tt < Tc; ++tt) {
        const int t = t0 + tt;
        const int p = (t - 1) & 1, np = t & 1;
        const u64 em = tagmask(t);

        // Prefetch pre_t (independent of the h chain).
        float pv[2][4];
#pragma unroll
        for (int j = 0; j < 2; ++j)
#pragma unroll
            for (int i = 0; i < 4; ++i)
                pv[j][i] = (float)preh[((size_t)(rows0 + quad * 4 + i) * Tc + tt) * H_DIM
                                       + c0w + j * 16 + lr];

        float4v acc0 = {0.f,0.f,0.f,0.f}, acc1 = {0.f,0.f,0.f,0.f};
        if (t > 0) {
            const f16* sb = stage[p];
#pragma unroll
            for (int kc = 0; kc < 16; ++kc) {
                half8 a = *(const half8*)&sb[lr * 512 + (((kc * 4 + quad) ^ (lr & 7)) * 8)];
                acc0 = __builtin_amdgcn_mfma_f32_16x16x32_f16(a, Bf[0][kc], acc0, 0, 0, 0);
                acc1 = __builtin_amdgcn_mfma_f32_16x16x32_f16(a, Bf[1][kc], acc1, 0, 0, 0);
            }
        }

        // Compute h_t slice; write own values (untagged) into stage[np].
        f16* sw = stage[np];
        f16 hv16[2][4];
#pragma unroll
        for (int j = 0; j < 2; ++j) {
            const float4v& a = j ? acc1 : acc0;
#pragma unroll
            for (int i = 0; i < 4; ++i) {
                float hval = fmaxf(a[i] + pv[j][i], 0.f);
                hv16[j][i] = (f16)hval;
                int row = quad * 4 + i, lc = c0w + j * 16 + lr;
                sw[row * 512 + ((lc >> 3) ^ (row & 7)) * 8 + (lc & 7)] = hv16[j][i];
            }
        }
        if (write_h) {
#pragma unroll
            for (int j = 0; j < 2; ++j)
#pragma unroll
                for (int i = 0; i < 4; ++i)
                    preh[((size_t)(rows0 + quad * 4 + i) * Tc + tt) * H_DIM
                         + c0w + j * 16 + lr] = hv16[j][i];
        }
        if (h_last && t == T_LEN - 1) {
#pragma unroll
            for (int j = 0; j < 2; ++j)
#pragma unroll
                for (int i = 0; i < 4; ++i)
                    h_last[(size_t)(rows0 + quad * 4 + i) * H_DIM + c0w + j * 16 + lr] =
                        (float)hv16[j][i];
        }
        if (tt == Tc - 1) {
#pragma unroll
            for (int j = 0; j < 2; ++j)
#pragma unroll
                for (int i = 0; i < 4; ++i)
                    hcarry[(size_t)(rows0 + quad * 4 + i) * H_DIM + c0w + j * 16 + lr] =
                        hv16[j][i];
        }
        __syncthreads();   // own-slice stage writes visible to publishers

        // Publish own 2 u64 (tagged) via device-scope atomic exchange.
        {
            int row = tid >> 4, poc = (tid & 15) * 2, cu = cg * 32 + poc;
            uint4 q4 = *(const uint4*)&stage[np][row * 512 + (((cu >> 1) ^ (row & 7)) * 8)];
            u64 v0 = (((u64)q4.y) << 32) | q4.x;
            u64 v1 = (((u64)q4.w) << 32) | q4.z;
            u64* dst = hex + ((size_t)np * 64 + rows0 + row) * 128;
            (void)__hip_atomic_exchange(&dst[cu], v0 | em, __ATOMIC_RELAXED,
                                        __HIP_MEMORY_SCOPE_AGENT);
            (void)__hip_atomic_exchange(&dst[cu + 1], v1 | em, __ATOMIC_RELAXED,
                                        __HIP_MEMORY_SCOPE_AGENT);
        }

        // Spin-read the 3 sibling slices (tag-validated), store into stage[np].
        if (!mine) {
            u64* src = hex + ((size_t)np * 64 + rows0 + rrow) * 128;
            u64 vv[8];
            int pend = 0xff, guard = 0;
            while (pend && guard < SPIN_LIM) {
#pragma unroll
                for (int q = 0; q < 8; ++q)
                    if (pend & (1 << q))
                        vv[q] = __hip_atomic_fetch_or(&src[rc8 + q], 0ull,
                                                      __ATOMIC_RELAXED,
                                                      __HIP_MEMORY_SCOPE_AGENT);
#pragma unroll
                for (int q = 0; q < 8; ++q)
                    if ((pend & (1 << q)) && ((vv[q] & SGN) == em))
                        pend &= ~(1 << q);
                ++guard;
            }
#pragma unroll
            for (int q = 0; q < 8; ++q) {
                int cu = rc8 + q;
                *(u64*)&stage[np][rrow * 512 + ((cu >> 1) ^ (rrow & 7)) * 8 + (cu & 1) * 4] =
                    vv[q] & VMASK;
            }
        }
        __syncthreads();   // stage[np] complete for step t+1
    }
}

// --------------------------- final FC --------------------------------------
__global__ void fc_kernel(const float* __restrict__ hlast, const f16* __restrict__ fcw,
                          const float* __restrict__ fcb, void* __restrict__ out,
                          const int* __restrict__ dtf) {
    int b = blockIdx.x, c = threadIdx.x;
    const float* hrow = hlast + b * H_DIM;
    const f16* wrow = fcw + (size_t)c * H_DIM;
    float s = fcb[c];
    for (int h0 = 0; h0 < H_DIM; h0 += 8) {
        half8 w = *(const half8*)(wrow + h0);
#pragma unroll
        for (int j = 0; j < 8; ++j) s += hrow[h0 + j] * (float)w[j];
    }
    if (*dtf) ((float*)out)[b * 128 + c] = s;
    else      ((u16*)out)[b * 128 + c] = f2bf(s);
}

// --------------------------- launch ----------------------------------------
extern "C" void kernel_launch(void* const* d_in, const int* in_sizes, int n_in,
                              void* d_out, int out_size, void* d_ws, size_t ws_size,
                              hipStream_t stream)
{
    const void* x     = d_in[0];
    const void* W_ih0 = d_in[1];
    const void* W_hh0 = d_in[2];
    const void* b_ih0 = d_in[3];
    const void* b_hh0 = d_in[4];
    const void* W_ih1 = d_in[5];
    const void* W_hh1 = d_in[6];
    const void* b_ih1 = d_in[7];
    const void* b_hh1 = d_in[8];
    const void* fc_w  = d_in[9];
    const void* fc_b  = d_in[10];

    char* ws = (char*)d_ws;
    int*   dtf   = (int*)(ws + 0);            //     64 B
    float* bias0 = (float*)(ws + 4096);       //   2048 B
    float* bias1 = (float*)(ws + 6144);       //   2048 B
    float* fcbf  = (float*)(ws + 8192);       //    512 B
    float* hlast = (float*)(ws + 16384);      // 131072 B
    f16*   hc0   = (f16*)(ws + 147456);       //  65536 B
    f16*   hc1   = (f16*)(ws + 212992);       //  65536 B
    u64*   hex0  = (u64*)(ws + 278528);       // 131072 B [2][64][128] u64
    u64*   hex1  = (u64*)(ws + 409600);       // 131072 B
    f16*   Wih0f = (f16*)(ws + 540672);       // 262144 B
    f16*   Whh0f = (f16*)(ws + 802816);       // 524288 B
    f16*   Wih1f = (f16*)(ws + 1327104);      // 524288 B
    f16*   Whh1f = (f16*)(ws + 1851392);      // 524288 B
    f16*   fcwf  = (f16*)(ws + 2375680);      // 131072 B

    const size_t misc = 4u << 20;
    int Tc = 128;
    {
        auto need = [&](int tc) {
            return misc + 2ull * B_SZ * (size_t)tc * H_DIM * 2;
        };
        if (ws_size >= need(2048)) Tc = 2048;
        else if (ws_size >= need(512)) Tc = 512;
        else if (ws_size >= need(256)) Tc = 256;
        else Tc = 128;
    }
    int lgTc = 31 - __builtin_clz((unsigned)Tc);
    const size_t bufbytes = (size_t)B_SZ * Tc * H_DIM * 2;
    f16* bufA = (f16*)(ws + misc);
    f16* bufB = (f16*)(ws + misc + bufbytes);

    detect_kernel<<<dim3(1), dim3(64), 0, stream>>>((const u16*)x, dtf);
    cvt_w_kernel<<<dim3(512), dim3(256), 0, stream>>>(W_ih0, Wih0f, H_DIM * 256, dtf);
    cvt_w_kernel<<<dim3(1024), dim3(256), 0, stream>>>(W_hh0, Whh0f, H_DIM * H_DIM, dtf);
    cvt_w_kernel<<<dim3(1024), dim3(256), 0, stream>>>(W_ih1, Wih1f, H_DIM * H_DIM, dtf);
    cvt_w_kernel<<<dim3(1024), dim3(256), 0, stream>>>(W_hh1, Whh1f, H_DIM * H_DIM, dtf);
    cvt_w_kernel<<<dim3(256), dim3(256), 0, stream>>>(fc_w, fcwf, 128 * H_DIM, dtf);
    bias_kernel<<<dim3(2), dim3(256), 0, stream>>>(b_ih0, b_hh0, bias0, dtf);
    bias_kernel<<<dim3(2), dim3(256), 0, stream>>>(b_ih1, b_hh1, bias1, dtf);
    fcb_kernel<<<dim3(1), dim3(128), 0, stream>>>(fc_b, fcbf, dtf);

    const int NC = T_LEN / Tc;
    const int mblocks = B_SZ * Tc / 64;
    for (int c = 0; c < NC; ++c) {
        const int t0 = c * Tc;
        gemm_tiled<1><<<dim3(mblocks, 8), 256, 0, stream>>>(
            x, Wih0f, bias0, bufA, lgTc, t0, 256, dtf);
        rnn_scan_kernel<<<dim3(16), 256, 0, stream>>>(
            bufA, Whh0f, hex0, hc0, t0, Tc, 1, nullptr);
        gemm_tiled<0><<<dim3(mblocks, 8), 256, 0, stream>>>(
            bufA, Wih1f, bias1, bufB, lgTc, 0, 512, dtf);
        rnn_scan_kernel<<<dim3(16), 256, 0, stream>>>(
            bufB, Whh1f, hex1, hc1, t0, Tc, 0, hlast);
    }
    fc_kernel<<<dim3(B_SZ), dim3(128), 0, stream>>>(hlast, fcwf, fcbf, d_out, dtf);
}